// Round 1
// baseline (392.100 us; speedup 1.0000x reference)
//
#include <hip/hip_runtime.h>
#include <stdint.h>

typedef unsigned short u16;
typedef __attribute__((ext_vector_type(8))) short bf16x8;
typedef __attribute__((ext_vector_type(4))) float f32x4;

__device__ inline u16 f2bf(float f) {
  union { float f; uint32_t u; } v; v.f = f;
  uint32_t u = v.u;
  u += 0x7FFFu + ((u >> 16) & 1u);
  return (u16)(u >> 16);
}

// async global->LDS, 16B per lane; LDS dest = wave-uniform base + lane*16
__device__ inline void gl_lds16(const void* g, void* s) {
  __builtin_amdgcn_global_load_lds(
      (const __attribute__((address_space(1))) void*)(uintptr_t)(g),
      (__attribute__((address_space(3))) void*)(uint32_t)(uintptr_t)(s),
      16, 0, 0);
}

__global__ void k_zero(float* p, int n) {
  int i = blockIdx.x * 256 + threadIdx.x;
  if (i < n) p[i] = 0.0f;
}

// partial mean of eigvs over N: acc[b][d] += sum_n eigvs[b][n][d]
__global__ void k_mean(const float* __restrict__ eig, float* __restrict__ acc) {
  const int b = blockIdx.y, chunk = blockIdx.x;
  const int t = threadIdx.x, d = t & 127, half = t >> 7;
  const float* p = eig + ((long)b * 4096 + chunk * 128 + half) * 128 + d;
  float s = 0.0f;
  for (int i = 0; i < 64; i++) s += p[(long)i * 256];
  __shared__ float red[256];
  red[t] = s;
  __syncthreads();
  if (t < 128) unsafeAtomicAdd(&acc[b * 128 + d], red[t] + red[t + 128]);
}

// coeff[b][0..4]=a, [5..9]=b, [10..14]=scale(sigmoid*5)
__global__ void k_coeff(const float* __restrict__ acc,
                        const float* __restrict__ Wa, const float* __restrict__ ba,
                        const float* __restrict__ Wb, const float* __restrict__ bb_,
                        const float* __restrict__ Ws, const float* __restrict__ bs,
                        float* __restrict__ coeff) {
  const int t = threadIdx.x;
  if (t >= 32) return;
  const int b = t >> 4, idx = t & 15;
  if (idx >= 15) return;
  const int kind = idx / 5, r = idx % 5;
  const float* W = (kind == 0) ? Wa : ((kind == 1) ? Wb : Ws);
  float s = 0.0f;
  for (int d = 0; d < 128; d++) s += acc[b * 128 + d] * (1.0f / 4096.0f) * W[d * 5 + r];
  s += (kind == 0) ? ba[r] : ((kind == 1) ? bb_[r] : bs[r]);
  if (kind == 2) s = 5.0f / (1.0f + __expf(-s));
  coeff[b * 16 + kind * 5 + r] = s;
}

// U fp32 [m][n] -> Ub bf16 [m][n] and Ut bf16 [n][m] (64x64 tiles via LDS)
__global__ void k_ucvt(const float* __restrict__ U, u16* __restrict__ Ub, u16* __restrict__ Ut) {
  const int b = blockIdx.z;
  const long base = (long)b * 4096 * 4096;
  const int tm = blockIdx.x, tn = blockIdx.y;
  const int t = threadIdx.x, cc = t & 63, rr = t >> 6;
  __shared__ u16 Ts[64][65];
#pragma unroll
  for (int p = 0; p < 16; p++) {
    const int r = p * 4 + rr;
    const float v = U[base + (long)(tm * 64 + r) * 4096 + tn * 64 + cc];
    const u16 h = f2bf(v);
    Ub[base + (long)(tm * 64 + r) * 4096 + tn * 64 + cc] = h;
    Ts[r][cc] = h;
  }
  __syncthreads();
#pragma unroll
  for (int p = 0; p < 16; p++) {
    const int n = p * 4 + rr;
    Ut[base + (long)(tn * 64 + n) * 4096 + tm * 64 + cc] = Ts[cc][n];
  }
}

// x fp32 [b][m][d] -> xT bf16 [b][d][m]
__global__ void k_xT(const float* __restrict__ x, u16* __restrict__ xT) {
  const int b = blockIdx.z, tm = blockIdx.x, td = blockIdx.y;
  const int t = threadIdx.x, cc = t & 63, rr = t >> 6;
  __shared__ u16 Ts[64][65];
#pragma unroll
  for (int p = 0; p < 16; p++) {
    const int r = p * 4 + rr;
    Ts[r][cc] = f2bf(x[((long)b * 4096 + tm * 64 + r) * 128 + td * 64 + cc]);
  }
  __syncthreads();
#pragma unroll
  for (int p = 0; p < 16; p++) {
    const int dl = p * 4 + rr;
    xT[((long)b * 128 + td * 64 + dl) * 4096 + tm * 64 + cc] = Ts[cc][dl];
  }
}

// VT[e][f*128+d] = (F_f @ Ww)[d][e], F_0=WS, F_{1+j}=WM[j]; bf16
__global__ void k_fold(const float* __restrict__ WS, const float* __restrict__ WM,
                       const float* __restrict__ Ww, u16* __restrict__ VT) {
  const int q = blockIdx.x, f = q >> 7, d = q & 127;
  const float* Frow = (f == 0) ? (WS + d * 128) : (WM + ((long)(f - 1) * 128 + d) * 128);
  const int e = threadIdx.x;
  float s = 0.0f;
  for (int k = 0; k < 128; k++) s += Frow[k] * Ww[k * 128 + e];
  VT[(long)e * 768 + f * 128 + d] = f2bf(s);
}

// c[e] = (bS + sum_j bM[j]) @ Ww + bw
__global__ void k_cbias(const float* __restrict__ bS, const float* __restrict__ bM,
                        const float* __restrict__ Ww, const float* __restrict__ bw,
                        float* __restrict__ c) {
  const int e = threadIdx.x;
  float s = bw[e];
  for (int k = 0; k < 128; k++) {
    float t = bS[k];
#pragma unroll
    for (int j = 0; j < 5; j++) t += bM[j * 128 + k];
    s += t * Ww[k * 128 + e];
  }
  c[e] = s;
}

// Mod[b][n][f*128+d]: f=0 -> h*xt, f=1..5 -> g_j*xt  (bf16)
__global__ void k_filter(const float* __restrict__ eig, const float* __restrict__ xt,
                         const float* __restrict__ coeff, u16* __restrict__ Mod) {
  const int b = blockIdx.y;
  const int n = blockIdx.x * 2 + (threadIdx.x >> 7);
  const int d = threadIdx.x & 127;
  const long ridx = (long)b * 4096 + n;
  const float e = eig[ridx * 128 + d];
  const float xv = xt[ridx * 128 + d];
  const float* cf = coeff + b * 16;
  // h = sum_i b_i * T_{2i}(e)
  float To = 1.0f, Tev = e;
  float h = cf[5];
#pragma unroll
  for (int i = 1; i < 5; i++) {
    To = 2.0f * e * Tev - To;
    Tev = 2.0f * e * To - Tev;
    h += cf[5 + i] * To;
  }
  u16* row = Mod + ridx * 768;
  row[d] = f2bf(h * xv);
#pragma unroll
  for (int j = 0; j < 5; j++) {
    const float sx = cf[10 + j] * e;
    float To2 = 1.0f, Te2 = sx;
    float g = cf[0] * Te2;
#pragma unroll
    for (int i = 1; i < 5; i++) {
      To2 = 2.0f * sx * Te2 - To2;
      Te2 = 2.0f * sx * To2 - Te2;
      g += cf[i] * Te2;
    }
    row[(j + 1) * 128 + d] = f2bf(g * xv);
  }
}

// Generic bf16 MFMA GEMM: C[row][col] = sum_k A[row][k]*B[col][k]
// A: [*][K] row-major bf16 (rows = output rows), B: [*][K] row-major bf16 (rows = output cols)
// MODE 0: fp32 atomicAdd out; MODE 1: + bias[col] on ks==0; MODE 2: bf16 plain store
template <int MODE>
__global__ __launch_bounds__(256) void k_gemm(
    const u16* __restrict__ A, long sA,
    const u16* __restrict__ B, long sB,
    void* __restrict__ C, long sC, int ldc,
    const float* __restrict__ bias,
    int K, int kchunk, int m_tiles) {
  __shared__ __align__(16) u16 As[128 * 32];
  __shared__ __align__(16) u16 Bs[128 * 32];
  const int bb = blockIdx.z, ks = blockIdx.y;
  const int tm = blockIdx.x % m_tiles, tn = blockIdx.x / m_tiles;
  const u16* Ab = A + (long)bb * sA + (long)tm * 128 * K + (long)ks * kchunk;
  const u16* Bb = B + (long)bb * sB + (long)tn * 128 * K + (long)ks * kchunk;
  const int tid = threadIdx.x, wave = tid >> 6, lane = tid & 63;
  const int wm = (wave >> 1) * 64, wn = (wave & 1) * 64;
  f32x4 acc[4][4];
#pragma unroll
  for (int i = 0; i < 4; i++)
#pragma unroll
    for (int j = 0; j < 4; j++)
#pragma unroll
      for (int r = 0; r < 4; r++) acc[i][j][r] = 0.0f;
  // fragment LDS byte offsets: tile rows of 32 bf16 = 64B
  const int a_off = (wm + (lane & 15)) * 64 + (lane >> 4) * 16;
  const int b_off = (wn + (lane & 15)) * 64 + (lane >> 4) * 16;
  // staging: wave covers rows [wave*32, wave*32+32), 2 issues of 16 rows
  const int srow = wave * 32 + (lane >> 2);
  const int scol = (lane & 3) * 8;
  for (int k0 = 0; k0 < kchunk; k0 += 32) {
#pragma unroll
    for (int i = 0; i < 2; i++) {
      gl_lds16(Ab + (long)(srow + i * 16) * K + k0 + scol,
               (char*)As + (wave * 32 + i * 16) * 64);
      gl_lds16(Bb + (long)(srow + i * 16) * K + k0 + scol,
               (char*)Bs + (wave * 32 + i * 16) * 64);
    }
    __syncthreads();
    bf16x8 af[4], bfr[4];
#pragma unroll
    for (int mt = 0; mt < 4; mt++)
      af[mt] = *(const bf16x8*)((const char*)As + a_off + mt * 1024);
#pragma unroll
    for (int nt = 0; nt < 4; nt++)
      bfr[nt] = *(const bf16x8*)((const char*)Bs + b_off + nt * 1024);
#pragma unroll
    for (int mt = 0; mt < 4; mt++)
#pragma unroll
      for (int nt = 0; nt < 4; nt++)
        acc[mt][nt] = __builtin_amdgcn_mfma_f32_16x16x32_bf16(af[mt], bfr[nt], acc[mt][nt], 0, 0, 0);
    __syncthreads();
  }
  const int lr = (lane >> 4) * 4, lc = lane & 15;
  if (MODE == 2) {
    u16* Cb = (u16*)C + (long)bb * sC;
#pragma unroll
    for (int mt = 0; mt < 4; mt++)
#pragma unroll
      for (int nt = 0; nt < 4; nt++) {
        const int col = tn * 128 + wn + nt * 16 + lc;
#pragma unroll
        for (int r = 0; r < 4; r++) {
          const int row = tm * 128 + wm + mt * 16 + lr + r;
          Cb[(long)row * ldc + col] = f2bf(acc[mt][nt][r]);
        }
      }
  } else {
    float* Cf = (float*)C + (long)bb * sC;
#pragma unroll
    for (int mt = 0; mt < 4; mt++)
#pragma unroll
      for (int nt = 0; nt < 4; nt++) {
        const int col = tn * 128 + wn + nt * 16 + lc;
        float bv = 0.0f;
        if (MODE == 1 && ks == 0) bv = bias[wn + nt * 16 + lc];
#pragma unroll
        for (int r = 0; r < 4; r++) {
          const int row = tm * 128 + wm + mt * 16 + lr + r;
          unsafeAtomicAdd(Cf + (long)row * ldc + col, acc[mt][nt][r] + bv);
        }
      }
  }
}

extern "C" void kernel_launch(void* const* d_in, const int* in_sizes, int n_in,
                              void* d_out, int out_size, void* d_ws, size_t ws_size,
                              hipStream_t stream) {
  const float* eig = (const float*)d_in[0];
  const float* x   = (const float*)d_in[1];
  const float* U   = (const float*)d_in[2];
  const float* Wa  = (const float*)d_in[3];
  const float* ba  = (const float*)d_in[4];
  const float* Wb  = (const float*)d_in[5];
  const float* bb  = (const float*)d_in[6];
  const float* Ws  = (const float*)d_in[7];
  const float* bs  = (const float*)d_in[8];
  const float* WSm = (const float*)d_in[9];
  const float* bS  = (const float*)d_in[10];
  const float* WM  = (const float*)d_in[11];
  const float* bM  = (const float*)d_in[12];
  const float* Ww  = (const float*)d_in[13];
  const float* bw  = (const float*)d_in[14];

  char* ws = (char*)d_ws;
  u16*   Ub   = (u16*)(ws + 0);            // 67,108,864 B
  u16*   Ut   = (u16*)(ws + 67108864);     // 67,108,864 B
  u16*   xT   = (u16*)(ws + 134217728);    //  2,097,152 B
  float* xt   = (float*)(ws + 136314880);  //  4,194,304 B
  u16*   Mod  = (u16*)(ws + 140509184);    // 12,582,912 B
  u16*   wT   = (u16*)(ws + 153092096);    //  2,097,152 B
  u16*   VT   = (u16*)(ws + 155189248);    //    196,608 B
  float* ebar = (float*)(ws + 155385856);  //      1,024 B
  float* coef = (float*)(ws + 155386880);  //        128 B
  float* cvec = (float*)(ws + 155387008);  //        512 B
  float* outp = (float*)d_out;

  if (ws_size < (size_t)155387520) return;  // workspace guard

  // zero accumulation buffers (ws/d_out are poisoned before every call)
  k_zero<<<4096, 256, 0, stream>>>(xt, 1048576);
  k_zero<<<4096, 256, 0, stream>>>(outp, 1048576);
  k_zero<<<1, 256, 0, stream>>>(ebar, 256);

  // pooled filter coefficients
  k_mean<<<dim3(32, 2), 256, 0, stream>>>(eig, ebar);
  k_coeff<<<1, 64, 0, stream>>>(ebar, Wa, ba, Wb, bb, Ws, bs, coef);

  // format conversions / weight folding
  k_ucvt<<<dim3(64, 64, 2), 256, 0, stream>>>(U, Ub, Ut);
  k_xT<<<dim3(64, 2, 2), 256, 0, stream>>>(x, xT);
  k_fold<<<768, 128, 0, stream>>>(WSm, WM, Ww, VT);
  k_cbias<<<1, 128, 0, stream>>>(bS, bM, Ww, bw, cvec);

  // xt[n][d] = sum_m U[m][n] x[m][d]   (A=Ut, B=xT), split-K=4
  k_gemm<0><<<dim3(32, 4, 2), 256, 0, stream>>>(
      Ut, 16777216L, xT, 524288L, (void*)xt, 524288L, 128, nullptr, 4096, 1024, 32);

  // modulated tensor (Chebyshev filters * xt), bf16
  k_filter<<<dim3(2048, 2), 256, 0, stream>>>(eig, xt, coef, Mod);

  // wT[e][m] = sum_k VT[e][k] Mod[m][k], K=768, bf16 out
  k_gemm<2><<<dim3(32, 1, 2), 256, 0, stream>>>(
      VT, 0L, Mod, 3145728L, (void*)wT, 524288L, 4096, nullptr, 768, 768, 1);

  // out[n][e] = sum_m U[n][m] wT[e][m] + c[e], split-K=4
  k_gemm<1><<<dim3(32, 4, 2), 256, 0, stream>>>(
      Ub, 16777216L, wT, 524288L, (void*)outp, 524288L, 128, cvec, 4096, 1024, 32);
}

// Round 3
// 368.773 us; speedup vs baseline: 1.0633x; 1.0633x over previous
//
#include <hip/hip_runtime.h>
#include <stdint.h>

typedef unsigned short u16;
typedef __attribute__((ext_vector_type(8))) short bf16x8;
typedef __attribute__((ext_vector_type(4))) float f32x4;
typedef __attribute__((ext_vector_type(4))) uint32_t u32x4;

__device__ inline u16 f2bf(float f) {
  union { float f; uint32_t u; } v; v.f = f;
  uint32_t u = v.u;
  u += 0x7FFFu + ((u >> 16) & 1u);
  return (u16)(u >> 16);
}

// async global->LDS, 16B per lane; LDS dest = wave-uniform base + lane*16
__device__ inline void gl_lds16(const void* g, void* s) {
  __builtin_amdgcn_global_load_lds(
      (const __attribute__((address_space(1))) void*)(uintptr_t)(g),
      (__attribute__((address_space(3))) void*)(uint32_t)(uintptr_t)(s),
      16, 0, 0);
}

__global__ void k_zero(float* p, int n) {
  int i = blockIdx.x * 256 + threadIdx.x;
  if (i < n) p[i] = 0.0f;
}

// partial mean of eigvs over N: acc[b][d] += sum_n eigvs[b][n][d]
__global__ void k_mean(const float* __restrict__ eig, float* __restrict__ acc) {
  const int b = blockIdx.y, chunk = blockIdx.x;
  const int t = threadIdx.x, d = t & 127, half = t >> 7;
  const float* p = eig + ((long)b * 4096 + chunk * 128 + half) * 128 + d;
  float s = 0.0f;
  for (int i = 0; i < 64; i++) s += p[(long)i * 256];
  __shared__ float red[256];
  red[t] = s;
  __syncthreads();
  if (t < 128) unsafeAtomicAdd(&acc[b * 128 + d], red[t] + red[t + 128]);
}

// coeff[b][0..4]=a, [5..9]=b, [10..14]=scale(sigmoid*5)
__global__ void k_coeff(const float* __restrict__ acc,
                        const float* __restrict__ Wa, const float* __restrict__ ba,
                        const float* __restrict__ Wb, const float* __restrict__ bb_,
                        const float* __restrict__ Ws, const float* __restrict__ bs,
                        float* __restrict__ coeff) {
  const int t = threadIdx.x;
  if (t >= 32) return;
  const int b = t >> 4, idx = t & 15;
  if (idx >= 15) return;
  const int kind = idx / 5, r = idx % 5;
  const float* W = (kind == 0) ? Wa : ((kind == 1) ? Wb : Ws);
  float s = 0.0f;
  for (int d = 0; d < 128; d++) s += acc[b * 128 + d] * (1.0f / 4096.0f) * W[d * 5 + r];
  s += (kind == 0) ? ba[r] : ((kind == 1) ? bb_[r] : bs[r]);
  if (kind == 2) s = 5.0f / (1.0f + __expf(-s));
  coeff[b * 16 + kind * 5 + r] = s;
}

// Generic transpose: in fp32 [R][C] (+b*inStride) -> out bf16 [C][R] (+b*outStride).
// 64x64 tiles; LDS holds u32 = packed pair of bf16 along the input-col axis.
__global__ __launch_bounds__(256) void k_trans(
    const float* __restrict__ in, u16* __restrict__ out,
    int R, int C, long inStride, long outStride) {
  const int b = blockIdx.z;
  const float* I = in + (long)b * inStride;
  u16* O = out + (long)b * outStride;
  const int tr = blockIdx.x;  // tile along R
  const int tc = blockIdx.y;  // tile along C
  __shared__ uint32_t L[64][33];
  const int t = threadIdx.x;
  // phase 1: row r = t>>2, 4 dense float4 loads at cols (t&3)*4 + 16*i
  const int r = t >> 2, cq = (t & 3) * 4;
  const float* src = I + (long)(tr * 64 + r) * C + tc * 64;
#pragma unroll
  for (int i = 0; i < 4; i++) {
    const float4 f = *(const float4*)(src + cq + 16 * i);
    const int c = cq + 16 * i;  // even
    L[r][(c >> 1)]     = (uint32_t)f2bf(f.x) | ((uint32_t)f2bf(f.y) << 16);
    L[r][(c >> 1) + 1] = (uint32_t)f2bf(f.z) | ((uint32_t)f2bf(f.w) << 16);
  }
  __syncthreads();
  // phase 2: output rows c (orig cols), contiguous along orig rows r.
  // thread: r0 = (t&7)*8, c = (t>>3) + 32*p ; 8 strided u32 reads, pick half, pack, 16B store
  const int r0 = (t & 7) * 8;
#pragma unroll
  for (int p = 0; p < 2; p++) {
    const int c = (t >> 3) + 32 * p;
    uint32_t w[4];
#pragma unroll
    for (int i = 0; i < 4; i++) {
      const uint32_t w0 = L[r0 + 2 * i][c >> 1];
      const uint32_t w1 = L[r0 + 2 * i + 1][c >> 1];
      const u16 v0 = (c & 1) ? (u16)(w0 >> 16) : (u16)(w0 & 0xffff);
      const u16 v1 = (c & 1) ? (u16)(w1 >> 16) : (u16)(w1 & 0xffff);
      w[i] = (uint32_t)v0 | ((uint32_t)v1 << 16);
    }
    u32x4* dst = (u32x4*)(O + (long)(tc * 64 + c) * R + tr * 64 + r0);
    *dst = u32x4{w[0], w[1], w[2], w[3]};
  }
}

// VT[e][f*128+d] = (F_f @ Ww)[d][e], F_0=WS, F_{1+j}=WM[j]; bf16
__global__ void k_fold(const float* __restrict__ WS, const float* __restrict__ WM,
                       const float* __restrict__ Ww, u16* __restrict__ VT) {
  const int q = blockIdx.x, f = q >> 7, d = q & 127;
  const float* Frow = (f == 0) ? (WS + d * 128) : (WM + ((long)(f - 1) * 128 + d) * 128);
  const int e = threadIdx.x;
  float s = 0.0f;
  for (int k = 0; k < 128; k++) s += Frow[k] * Ww[k * 128 + e];
  VT[(long)e * 768 + f * 128 + d] = f2bf(s);
}

// c[e] = (bS + sum_j bM[j]) @ Ww + bw
__global__ void k_cbias(const float* __restrict__ bS, const float* __restrict__ bM,
                        const float* __restrict__ Ww, const float* __restrict__ bw,
                        float* __restrict__ c) {
  const int e = threadIdx.x;
  float s = bw[e];
  for (int k = 0; k < 128; k++) {
    float t = bS[k];
#pragma unroll
    for (int j = 0; j < 5; j++) t += bM[j * 128 + k];
    s += t * Ww[k * 128 + e];
  }
  c[e] = s;
}

// Reduce 4 split-K slices of xt, apply Chebyshev filters, emit Mod bf16.
// Mod[b][n][f*128+d]: f=0 -> h*xt, f=1..5 -> g_j*xt
__global__ void k_filter(const float* __restrict__ eig, const float* __restrict__ xs,
                         const float* __restrict__ coeff, u16* __restrict__ Mod) {
  const int b = blockIdx.y;
  const int n = blockIdx.x * 2 + (threadIdx.x >> 7);
  const int d = threadIdx.x & 127;
  const long ridx = (long)b * 4096 + n;
  const long off = ridx * 128 + d;
  const float e = eig[off];
  const float xv = xs[off] + xs[off + 1048576] + xs[off + 2097152] + xs[off + 3145728];
  const float* cf = coeff + b * 16;
  // h: odd Chebyshev polys per reference _generate_h
  float To = 1.0f, Tev = e;
  float h = cf[5];
#pragma unroll
  for (int i = 1; i < 5; i++) {
    To = 2.0f * e * Tev - To;
    Tev = 2.0f * e * To - Tev;
    h += cf[5 + i] * To;
  }
  u16* row = Mod + ridx * 768;
  row[d] = f2bf(h * xv);
#pragma unroll
  for (int j = 0; j < 5; j++) {
    const float sx = cf[10 + j] * e;
    float To2 = 1.0f, Te2 = sx;
    float g = cf[0] * Te2;
#pragma unroll
    for (int i = 1; i < 5; i++) {
      To2 = 2.0f * sx * Te2 - To2;
      Te2 = 2.0f * sx * To2 - Te2;
      g += cf[i] * Te2;
    }
    row[(j + 1) * 128 + d] = f2bf(g * xv);
  }
}

// out[b][n][e] = sum_s os[s][b][n][e] + cvec[e]   (vectorized float4)
__global__ void k_outred(const float* __restrict__ os, const float* __restrict__ cvec,
                         float* __restrict__ out) {
  const int i = blockIdx.x * 256 + threadIdx.x;  // over 262144 float4s
  const float4 a = *(const float4*)(os + 4L * i);
  const float4 b = *(const float4*)(os + 4L * i + 1048576);
  const float4 c = *(const float4*)(os + 4L * i + 2097152);
  const float4 d = *(const float4*)(os + 4L * i + 3145728);
  const float4 cv = *(const float4*)(cvec + (i & 31) * 4);
  float4 r;
  r.x = a.x + b.x + c.x + d.x + cv.x;
  r.y = a.y + b.y + c.y + d.y + cv.y;
  r.z = a.z + b.z + c.z + d.z + cv.z;
  r.w = a.w + b.w + c.w + d.w + cv.w;
  *(float4*)(out + 4L * i) = r;
}

// Generic bf16 MFMA GEMM: C[row][col] = sum_k A[row][k]*B[col][k]
// B: bf16 [*][K] staged via global_load_lds.
// A32=false: A bf16 [*][K] staged via global_load_lds.
// A32=true:  A fp32 [*][K], loaded to regs, converted, ds_write_b128 to LDS.
// MODE 2: bf16 plain store. MODE 3: fp32 plain store to slice C + ks*kslice.
template <int MODE, bool A32>
__global__ __launch_bounds__(256) void k_gemm(
    const void* __restrict__ A, long sA,
    const u16* __restrict__ B, long sB,
    void* __restrict__ C, long sC, int ldc, long kslice,
    int K, int kchunk, int m_tiles) {
  __shared__ __align__(16) u16 As[128 * 32];
  __shared__ __align__(16) u16 Bs[128 * 32];
  const int bb = blockIdx.z, ks = blockIdx.y;
  const int tm = blockIdx.x % m_tiles, tn = blockIdx.x / m_tiles;
  const u16* Ab = (const u16*)A + (long)bb * sA + (long)tm * 128 * K + (long)ks * kchunk;
  const float* Af = (const float*)A + (long)bb * sA + (long)tm * 128 * K + (long)ks * kchunk;
  const u16* Bb = B + (long)bb * sB + (long)tn * 128 * K + (long)ks * kchunk;
  const int tid = threadIdx.x, wave = tid >> 6, lane = tid & 63;
  const int wm = (wave >> 1) * 64, wn = (wave & 1) * 64;
  f32x4 acc[4][4];
#pragma unroll
  for (int i = 0; i < 4; i++)
#pragma unroll
    for (int j = 0; j < 4; j++)
#pragma unroll
      for (int r = 0; r < 4; r++) acc[i][j][r] = 0.0f;
  const int a_off = (wm + (lane & 15)) * 64 + (lane >> 4) * 16;
  const int b_off = (wn + (lane & 15)) * 64 + (lane >> 4) * 16;
  const int srow = wave * 32 + (lane >> 2);
  const int scol = (lane & 3) * 8;
  for (int k0 = 0; k0 < kchunk; k0 += 32) {
    if constexpr (A32) {
      // A tile 128 rows x 32 k fp32 -> bf16 LDS. thread: row=tid>>1, kk=(tid&1)*16
      const float* src = Af + (long)(tid >> 1) * K + k0 + (tid & 1) * 16;
      const float4 f0 = *(const float4*)(src);
      const float4 f1 = *(const float4*)(src + 4);
      const float4 f2 = *(const float4*)(src + 8);
      const float4 f3 = *(const float4*)(src + 12);
      const float vv[16] = {f0.x, f0.y, f0.z, f0.w, f1.x, f1.y, f1.z, f1.w,
                            f2.x, f2.y, f2.z, f2.w, f3.x, f3.y, f3.z, f3.w};
      uint32_t w[8];
#pragma unroll
      for (int i = 0; i < 8; i++)
        w[i] = (uint32_t)f2bf(vv[2 * i]) | ((uint32_t)f2bf(vv[2 * i + 1]) << 16);
      u32x4* dst = (u32x4*)((char*)As + (tid >> 1) * 64 + (tid & 1) * 32);
      dst[0] = u32x4{w[0], w[1], w[2], w[3]};
      dst[1] = u32x4{w[4], w[5], w[6], w[7]};
    } else {
#pragma unroll
      for (int i = 0; i < 2; i++)
        gl_lds16(Ab + (long)(srow + i * 16) * K + k0 + scol,
                 (char*)As + (wave * 32 + i * 16) * 64);
    }
#pragma unroll
    for (int i = 0; i < 2; i++)
      gl_lds16(Bb + (long)(srow + i * 16) * K + k0 + scol,
               (char*)Bs + (wave * 32 + i * 16) * 64);
    __syncthreads();
    bf16x8 af[4], bfr[4];
#pragma unroll
    for (int mt = 0; mt < 4; mt++)
      af[mt] = *(const bf16x8*)((const char*)As + a_off + mt * 1024);
#pragma unroll
    for (int nt = 0; nt < 4; nt++)
      bfr[nt] = *(const bf16x8*)((const char*)Bs + b_off + nt * 1024);
#pragma unroll
    for (int mt = 0; mt < 4; mt++)
#pragma unroll
      for (int nt = 0; nt < 4; nt++)
        acc[mt][nt] = __builtin_amdgcn_mfma_f32_16x16x32_bf16(af[mt], bfr[nt], acc[mt][nt], 0, 0, 0);
    __syncthreads();
  }
  const int lr = (lane >> 4) * 4, lc = lane & 15;
  if constexpr (MODE == 2) {
    u16* Cb = (u16*)C + (long)bb * sC;
#pragma unroll
    for (int mt = 0; mt < 4; mt++)
#pragma unroll
      for (int nt = 0; nt < 4; nt++) {
        const int col = tn * 128 + wn + nt * 16 + lc;
#pragma unroll
        for (int r = 0; r < 4; r++) {
          const int row = tm * 128 + wm + mt * 16 + lr + r;
          Cb[(long)row * ldc + col] = f2bf(acc[mt][nt][r]);
        }
      }
  } else {
    float* Cf = (float*)C + (long)bb * sC + (long)ks * kslice;
#pragma unroll
    for (int mt = 0; mt < 4; mt++)
#pragma unroll
      for (int nt = 0; nt < 4; nt++) {
        const int col = tn * 128 + wn + nt * 16 + lc;
#pragma unroll
        for (int r = 0; r < 4; r++) {
          const int row = tm * 128 + wm + mt * 16 + lr + r;
          Cf[(long)row * ldc + col] = acc[mt][nt][r];
        }
      }
  }
}

extern "C" void kernel_launch(void* const* d_in, const int* in_sizes, int n_in,
                              void* d_out, int out_size, void* d_ws, size_t ws_size,
                              hipStream_t stream) {
  const float* eig = (const float*)d_in[0];
  const float* x   = (const float*)d_in[1];
  const float* U   = (const float*)d_in[2];
  const float* Wa  = (const float*)d_in[3];
  const float* ba  = (const float*)d_in[4];
  const float* Wb  = (const float*)d_in[5];
  const float* bb  = (const float*)d_in[6];
  const float* Ws  = (const float*)d_in[7];
  const float* bs  = (const float*)d_in[8];
  const float* WSm = (const float*)d_in[9];
  const float* bS  = (const float*)d_in[10];
  const float* WM  = (const float*)d_in[11];
  const float* bM  = (const float*)d_in[12];
  const float* Ww  = (const float*)d_in[13];
  const float* bw  = (const float*)d_in[14];

  char* ws = (char*)d_ws;
  u16*   Ut   = (u16*)(ws + 0);            // 67,108,864 B
  u16*   xT   = (u16*)(ws + 67108864);     //  2,097,152 B
  float* xs   = (float*)(ws + 69206016);   // 16,777,216 B (4 split-K slices)
  u16*   Mod  = (u16*)(ws + 85983232);     // 12,582,912 B
  u16*   wT   = (u16*)(ws + 98566144);     //  2,097,152 B
  float* os   = (float*)(ws + 100663296);  // 16,777,216 B (4 split-K slices)
  u16*   VT   = (u16*)(ws + 117440512);    //    196,608 B
  float* ebar = (float*)(ws + 117637120);  //      1,024 B
  float* coef = (float*)(ws + 117638144);  //        128 B
  float* cvec = (float*)(ws + 117638272);  //        512 B
  float* outp = (float*)d_out;

  if (ws_size < (size_t)117638784) return;  // workspace guard

  // pooled filter coefficients
  k_zero<<<1, 256, 0, stream>>>(ebar, 256);
  k_mean<<<dim3(32, 2), 256, 0, stream>>>(eig, ebar);
  k_coeff<<<1, 64, 0, stream>>>(ebar, Wa, ba, Wb, bb, Ws, bs, coef);

  // transposes: Ut[n][m] = bf16(U[m][n]);  xT[d][m] = bf16(x[m][d])
  k_trans<<<dim3(64, 64, 2), 256, 0, stream>>>(U, Ut, 4096, 4096, 16777216L, 16777216L);
  k_trans<<<dim3(64, 2, 2), 256, 0, stream>>>(x, xT, 4096, 128, 524288L, 524288L);

  // weight folding
  k_fold<<<768, 128, 0, stream>>>(WSm, WM, Ww, VT);
  k_cbias<<<1, 128, 0, stream>>>(bS, bM, Ww, bw, cvec);

  // GEMM1: xt[n][d] = sum_m U[m][n] x[m][d]  (A=Ut bf16, B=xT bf16), split-K=4 -> xs slices
  k_gemm<3, false><<<dim3(32, 4, 2), 256, 0, stream>>>(
      Ut, 16777216L, xT, 524288L, (void*)xs, 524288L, 128, 1048576L, 4096, 1024, 32);

  // reduce slices + Chebyshev filters -> Mod bf16
  k_filter<<<dim3(2048, 2), 256, 0, stream>>>(eig, xs, coef, Mod);

  // GEMM2: wT[e][m] = sum_k VT[e][k] Mod[m][k], K=768, bf16 out
  k_gemm<2, false><<<dim3(32, 1, 2), 256, 0, stream>>>(
      VT, 0L, Mod, 3145728L, (void*)wT, 524288L, 4096, 0L, 768, 768, 1);

  // GEMM3: out[n][e] = sum_m U[n][m] wT[e][m]  (A=U fp32 direct, B=wT bf16), split-K=4 -> os
  k_gemm<3, true><<<dim3(32, 4, 2), 256, 0, stream>>>(
      U, 16777216L, wT, 524288L, (void*)os, 524288L, 128, 1048576L, 4096, 1024, 32);

  // final reduce + bias
  k_outred<<<1024, 256, 0, stream>>>(os, cvec, outp);
}

// Round 4
// 319.880 us; speedup vs baseline: 1.2258x; 1.1528x over previous
//
#include <hip/hip_runtime.h>
#include <hip/hip_bf16.h>
#include <stdint.h>

typedef unsigned short u16;
typedef __attribute__((ext_vector_type(8))) short bf16x8;
typedef __attribute__((ext_vector_type(4))) float f32x4;
typedef __attribute__((ext_vector_type(4))) uint32_t u32x4;

__device__ inline u16 f2bf(float f) {
  union { float f; uint32_t u; } v; v.f = f;
  uint32_t u = v.u;
  u += 0x7FFFu + ((u >> 16) & 1u);
  return (u16)(u >> 16);
}

// packed 2x fp32 -> bf16 pair in one u32 (lo = a, hi = b), RNE
__device__ inline uint32_t pkbf(float a, float b) {
  union { __hip_bfloat162 h; uint32_t u; } c;
  c.h = __float22bfloat162_rn(float2{a, b});
  return c.u;
}

// async global->LDS, 16B per lane; LDS dest = wave-uniform base + lane*16
__device__ inline void gl_lds16(const void* g, void* s) {
  __builtin_amdgcn_global_load_lds(
      (const __attribute__((address_space(1))) void*)(uintptr_t)(g),
      (__attribute__((address_space(3))) void*)(uint32_t)(uintptr_t)(s),
      16, 0, 0);
}

// ---- pooled coefficients --------------------------------------------------
// partial sums of eigvs over N: part[(b*32+chunk)][d]
__global__ void k_mean(const float* __restrict__ eig, float* __restrict__ part) {
  const int b = blockIdx.y, chunk = blockIdx.x;
  const int t = threadIdx.x, d = t & 127, half = t >> 7;
  const float* p = eig + ((long)b * 4096 + chunk * 128 + half) * 128 + d;
  float s = 0.0f;
  for (int i = 0; i < 64; i++) s += p[(long)i * 256];
  __shared__ float red[256];
  red[t] = s;
  __syncthreads();
  if (t < 128) part[((long)b * 32 + chunk) * 128 + d] = red[t] + red[t + 128];
}

// coeff[b][0..4]=a, [5..9]=b, [10..14]=scale(sigmoid*5)
__global__ void k_coeff(const float* __restrict__ part,
                        const float* __restrict__ Wa, const float* __restrict__ ba,
                        const float* __restrict__ Wb, const float* __restrict__ bb_,
                        const float* __restrict__ Ws, const float* __restrict__ bs,
                        float* __restrict__ coeff) {
  const int b = blockIdx.x, t = threadIdx.x;
  __shared__ float sd[128];
  float s = 0.0f;
  for (int c = 0; c < 32; c++) s += part[((long)b * 32 + c) * 128 + t];
  sd[t] = s * (1.0f / 4096.0f);
  __syncthreads();
  if (t >= 15) return;
  const int kind = t / 5, r = t % 5;
  const float* W = (kind == 0) ? Wa : ((kind == 1) ? Wb : Ws);
  float v = 0.0f;
  for (int d = 0; d < 128; d++) v += sd[d] * W[d * 5 + r];
  v += (kind == 0) ? ba[r] : ((kind == 1) ? bb_[r] : bs[r]);
  if (kind == 2) v = 5.0f / (1.0f + __expf(-v));
  coeff[b * 16 + kind * 5 + r] = v;
}

// ---- weight folding -------------------------------------------------------
// blocks 0..767: VT[e][f*128+d] = (F_f @ Ww)[d][e]; block 768: cvec
__global__ void k_fold(const float* __restrict__ WS, const float* __restrict__ WM,
                       const float* __restrict__ Ww, const float* __restrict__ bS,
                       const float* __restrict__ bM, const float* __restrict__ bw,
                       u16* __restrict__ VT, float* __restrict__ cvec) {
  const int q = blockIdx.x;
  const int e = threadIdx.x;
  if (q == 768) {
    float s = bw[e];
    for (int k = 0; k < 128; k++) {
      float t = bS[k];
#pragma unroll
      for (int j = 0; j < 5; j++) t += bM[j * 128 + k];
      s += t * Ww[k * 128 + e];
    }
    cvec[e] = s;
    return;
  }
  const int f = q >> 7, d = q & 127;
  const float* Frow = (f == 0) ? (WS + d * 128) : (WM + ((long)(f - 1) * 128 + d) * 128);
  float s = 0.0f;
  for (int k = 0; k < 128; k++) s += Frow[k] * Ww[k * 128 + e];
  VT[(long)e * 768 + f * 128 + d] = f2bf(s);
}

// ---- elementwise stages ---------------------------------------------------
// Reduce 8 split-K slices of xt, apply Chebyshev filters, emit Mod bf16.
__global__ void k_filter(const float* __restrict__ eig, const float* __restrict__ xs,
                         const float* __restrict__ coeff, u16* __restrict__ Mod) {
  const int b = blockIdx.y;
  const int n = blockIdx.x * 2 + (threadIdx.x >> 7);
  const int d = threadIdx.x & 127;
  const long ridx = (long)b * 4096 + n;
  const long off = ridx * 128 + d;
  const float e = eig[off];
  float xv = 0.0f;
#pragma unroll
  for (int s = 0; s < 8; s++) xv += xs[off + (long)s * 1048576];
  const float* cf = coeff + b * 16;
  float To = 1.0f, Tev = e;
  float h = cf[5];
#pragma unroll
  for (int i = 1; i < 5; i++) {
    To = 2.0f * e * Tev - To;
    Tev = 2.0f * e * To - Tev;
    h += cf[5 + i] * To;
  }
  u16* row = Mod + ridx * 768;
  row[d] = f2bf(h * xv);
#pragma unroll
  for (int j = 0; j < 5; j++) {
    const float sx = cf[10 + j] * e;
    float To2 = 1.0f, Te2 = sx;
    float g = cf[0] * Te2;
#pragma unroll
    for (int i = 1; i < 5; i++) {
      To2 = 2.0f * sx * Te2 - To2;
      Te2 = 2.0f * sx * To2 - Te2;
      g += cf[i] * Te2;
    }
    row[(j + 1) * 128 + d] = f2bf(g * xv);
  }
}

// reduce 4 GEMM2 slices -> bf16 wT
__global__ void k_wred(const float* __restrict__ wsl, u16* __restrict__ wT) {
  const long i = ((long)blockIdx.x * 256 + threadIdx.x) * 4;
  float4 s = *(const float4*)(wsl + i);
#pragma unroll
  for (int k = 1; k < 4; k++) {
    const float4 t = *(const float4*)(wsl + i + (long)k * 1048576);
    s.x += t.x; s.y += t.y; s.z += t.z; s.w += t.w;
  }
  uint32_t lo = pkbf(s.x, s.y), hi = pkbf(s.z, s.w);
  *(uint2*)(wT + i) = uint2{lo, hi};
}

// out = sum of 8 GEMM3 slices + cvec
__global__ void k_outred(const float* __restrict__ os, const float* __restrict__ cvec,
                         float* __restrict__ out) {
  const long i = (long)blockIdx.x * 256 + threadIdx.x;  // over 262144 float4s
  float4 r = *(const float4*)(os + 4 * i);
#pragma unroll
  for (int s = 1; s < 8; s++) {
    const float4 t = *(const float4*)(os + 4 * i + (long)s * 1048576);
    r.x += t.x; r.y += t.y; r.z += t.z; r.w += t.w;
  }
  const float4 cv = *(const float4*)(cvec + (i & 31) * 4);
  r.x += cv.x; r.y += cv.y; r.z += cv.z; r.w += cv.w;
  *(float4*)(out + 4 * i) = r;
}

// ---- GEMM -----------------------------------------------------------------
// Transposing fp32 stage: global [k][cols] (k-row stride lda) -> LDS bf16 [col][32k]
// thread t: k-pair q = t&15, col-chunk cb = t>>4 (8 cols).
__device__ inline void stage_t32(const float* __restrict__ srcK, int lda,
                                 u16* __restrict__ lds, int t) {
  const int q = t & 15, cb = t >> 4;
  const float* r0 = srcK + (long)(2 * q) * lda + cb * 8;
  const float* r1 = r0 + lda;
  const float4 a0 = *(const float4*)(r0);
  const float4 a1 = *(const float4*)(r0 + 4);
  const float4 b0 = *(const float4*)(r1);
  const float4 b1 = *(const float4*)(r1 + 4);
  uint32_t* d = (uint32_t*)lds;
  const int base = cb * 128 + q;  // (cb*8+j)*16 + q
  d[base +   0] = pkbf(a0.x, b0.x);
  d[base +  16] = pkbf(a0.y, b0.y);
  d[base +  32] = pkbf(a0.z, b0.z);
  d[base +  48] = pkbf(a0.w, b0.w);
  d[base +  64] = pkbf(a1.x, b1.x);
  d[base +  80] = pkbf(a1.y, b1.y);
  d[base +  96] = pkbf(a1.z, b1.z);
  d[base + 112] = pkbf(a1.w, b1.w);
}

// C[row][col] = sum_k A[row][k]*B[col][k]; fp32 slice store at C + bb*sC + ks*kslice.
// AT/BT: 0 = bf16 [row][K] via global_load_lds; 1 = fp32 [row][K] reg-convert;
//        2 = fp32 [k][row] transposing stage.
template <int AT, int BT>
__global__ __launch_bounds__(256) void k_gemm(
    const void* __restrict__ A, long sA, int lda,
    const void* __restrict__ B, long sB, int ldb,
    float* __restrict__ C, long sC, int ldc, long kslice,
    int K, int kchunk, int m_tiles) {
  __shared__ __align__(16) u16 As[128 * 32];
  __shared__ __align__(16) u16 Bs[128 * 32];
  const int bb = blockIdx.z, ks = blockIdx.y;
  const int tm = blockIdx.x % m_tiles, tn = blockIdx.x / m_tiles;
  const int tid = threadIdx.x, wave = tid >> 6, lane = tid & 63;
  const int wm = (wave >> 1) * 64, wn = (wave & 1) * 64;
  f32x4 acc[4][4];
#pragma unroll
  for (int i = 0; i < 4; i++)
#pragma unroll
    for (int j = 0; j < 4; j++)
#pragma unroll
      for (int r = 0; r < 4; r++) acc[i][j][r] = 0.0f;
  const int a_off = (wm + (lane & 15)) * 64 + (lane >> 4) * 16;
  const int b_off = (wn + (lane & 15)) * 64 + (lane >> 4) * 16;
  const int srow = wave * 32 + (lane >> 2);
  const int scol = (lane & 3) * 8;
  for (int k0 = 0; k0 < kchunk; k0 += 32) {
    const int kb = ks * kchunk + k0;
    // ---- stage A
    if constexpr (AT == 0) {
      const u16* Ab = (const u16*)A + (long)bb * sA + (long)tm * 128 * lda + kb;
#pragma unroll
      for (int i = 0; i < 2; i++)
        gl_lds16(Ab + (long)(srow + i * 16) * lda + scol,
                 (char*)As + (wave * 32 + i * 16) * 64);
    } else if constexpr (AT == 1) {
      const float* src = (const float*)A + (long)bb * sA +
                         (long)(tm * 128 + (tid >> 1)) * lda + kb + (tid & 1) * 16;
      const float4 f0 = *(const float4*)(src);
      const float4 f1 = *(const float4*)(src + 4);
      const float4 f2 = *(const float4*)(src + 8);
      const float4 f3 = *(const float4*)(src + 12);
      u32x4* dst = (u32x4*)((char*)As + (tid >> 1) * 64 + (tid & 1) * 32);
      dst[0] = u32x4{pkbf(f0.x, f0.y), pkbf(f0.z, f0.w), pkbf(f1.x, f1.y), pkbf(f1.z, f1.w)};
      dst[1] = u32x4{pkbf(f2.x, f2.y), pkbf(f2.z, f2.w), pkbf(f3.x, f3.y), pkbf(f3.z, f3.w)};
    } else {
      const float* src = (const float*)A + (long)bb * sA + (long)kb * lda + tm * 128;
      stage_t32(src, lda, As, tid);
    }
    // ---- stage B
    if constexpr (BT == 0) {
      const u16* Bb = (const u16*)B + (long)bb * sB + (long)tn * 128 * ldb + kb;
#pragma unroll
      for (int i = 0; i < 2; i++)
        gl_lds16(Bb + (long)(srow + i * 16) * ldb + scol,
                 (char*)Bs + (wave * 32 + i * 16) * 64);
    } else {
      const float* src = (const float*)B + (long)bb * sB + (long)kb * ldb + tn * 128;
      stage_t32(src, ldb, Bs, tid);
    }
    __syncthreads();
    bf16x8 af[4], bfr[4];
#pragma unroll
    for (int mt = 0; mt < 4; mt++)
      af[mt] = *(const bf16x8*)((const char*)As + a_off + mt * 1024);
#pragma unroll
    for (int nt = 0; nt < 4; nt++)
      bfr[nt] = *(const bf16x8*)((const char*)Bs + b_off + nt * 1024);
#pragma unroll
    for (int mt = 0; mt < 4; mt++)
#pragma unroll
      for (int nt = 0; nt < 4; nt++)
        acc[mt][nt] = __builtin_amdgcn_mfma_f32_16x16x32_bf16(af[mt], bfr[nt], acc[mt][nt], 0, 0, 0);
    __syncthreads();
  }
  const int lr = (lane >> 4) * 4, lc = lane & 15;
  float* Cf = C + (long)bb * sC + (long)ks * kslice;
#pragma unroll
  for (int mt = 0; mt < 4; mt++)
#pragma unroll
    for (int nt = 0; nt < 4; nt++) {
      const int col = tn * 128 + wn + nt * 16 + lc;
#pragma unroll
      for (int r = 0; r < 4; r++) {
        const int row = tm * 128 + wm + mt * 16 + lr + r;
        Cf[(long)row * ldc + col] = acc[mt][nt][r];
      }
    }
}

extern "C" void kernel_launch(void* const* d_in, const int* in_sizes, int n_in,
                              void* d_out, int out_size, void* d_ws, size_t ws_size,
                              hipStream_t stream) {
  const float* eig = (const float*)d_in[0];
  const float* x   = (const float*)d_in[1];
  const float* U   = (const float*)d_in[2];
  const float* Wa  = (const float*)d_in[3];
  const float* ba  = (const float*)d_in[4];
  const float* Wb  = (const float*)d_in[5];
  const float* bb  = (const float*)d_in[6];
  const float* Ws  = (const float*)d_in[7];
  const float* bs  = (const float*)d_in[8];
  const float* WSm = (const float*)d_in[9];
  const float* bS  = (const float*)d_in[10];
  const float* WM  = (const float*)d_in[11];
  const float* bM  = (const float*)d_in[12];
  const float* Ww  = (const float*)d_in[13];
  const float* bw  = (const float*)d_in[14];

  char* ws = (char*)d_ws;
  float* xs   = (float*)(ws + 0);          // 33,554,432 B (8 split-K slices)
  u16*   Mod  = (u16*)(ws + 33554432);     // 12,582,912 B
  u16*   VT   = (u16*)(ws + 46137344);     //    196,608 B
  float* wsl  = (float*)(ws + 46333952);   // 16,777,216 B (4 GEMM2 slices)
  u16*   wT   = (u16*)(ws + 63111168);     //  2,097,152 B
  float* os   = (float*)(ws + 65208320);   // 33,554,432 B (8 split-K slices)
  float* part = (float*)(ws + 98762752);   //     32,768 B
  float* coef = (float*)(ws + 98795520);   //        128 B
  float* cvec = (float*)(ws + 98795648);   //        512 B
  float* outp = (float*)d_out;

  if (ws_size < (size_t)98796160) return;  // workspace guard

  // pooled filter coefficients
  k_mean<<<dim3(32, 2), 256, 0, stream>>>(eig, part);
  k_coeff<<<2, 128, 0, stream>>>(part, Wa, ba, Wb, bb, Ws, bs, coef);

  // weight folding (+ bias vector, block 768)
  k_fold<<<769, 128, 0, stream>>>(WSm, WM, Ww, bS, bM, bw, VT, cvec);

  // GEMM1: xt[n][d] = sum_m U[m][n] x[m][d]; A = U fp32 [k=m][n] transposed-stage,
  // B = x fp32 [k=m][d] transposed-stage; split-K=8 -> xs slices
  k_gemm<2, 2><<<dim3(32, 8, 2), 256, 0, stream>>>(
      U, 16777216L, 4096, x, 524288L, 128,
      xs, 524288L, 128, 1048576L, 4096, 512, 32);

  // reduce slices + Chebyshev filters -> Mod bf16
  k_filter<<<dim3(2048, 2), 256, 0, stream>>>(eig, xs, coef, Mod);

  // GEMM2: wT[e][m] = sum_k VT[e][k] Mod[m][k]; split-K=4 -> wsl slices
  k_gemm<0, 0><<<dim3(32, 4, 2), 256, 0, stream>>>(
      VT, 0L, 768, Mod, 3145728L, 768,
      wsl, 524288L, 4096, 1048576L, 768, 192, 1);
  k_wred<<<1024, 256, 0, stream>>>(wsl, wT);

  // GEMM3: out[n][e] = sum_m U[n][m] wT[e][m]; A = U fp32 row-direct; split-K=8 -> os
  k_gemm<1, 0><<<dim3(32, 8, 2), 256, 0, stream>>>(
      U, 16777216L, 4096, wT, 524288L, 4096,
      os, 524288L, 128, 1048576L, 4096, 512, 32);

  // final reduce + bias
  k_outred<<<1024, 256, 0, stream>>>(os, cvec, outp);
}

// Round 5
// 312.843 us; speedup vs baseline: 1.2533x; 1.0225x over previous
//
#include <hip/hip_runtime.h>
#include <hip/hip_bf16.h>
#include <stdint.h>

typedef unsigned short u16;
typedef __attribute__((ext_vector_type(8))) short bf16x8;
typedef __attribute__((ext_vector_type(4))) float f32x4;
typedef __attribute__((ext_vector_type(4))) uint32_t u32x4;

__device__ inline u16 f2bf(float f) {
  union { float f; uint32_t u; } v; v.f = f;
  uint32_t u = v.u;
  u += 0x7FFFu + ((u >> 16) & 1u);
  return (u16)(u >> 16);
}

// packed 2x fp32 -> bf16 pair in one u32 (lo = a, hi = b), RNE
__device__ inline uint32_t pkbf(float a, float b) {
  union { __hip_bfloat162 h; uint32_t u; } c;
  c.h = __float22bfloat162_rn(float2{a, b});
  return c.u;
}

// async global->LDS, 16B per lane; LDS dest = wave-uniform base + lane*16
__device__ inline void gl_lds16(const void* g, void* s) {
  __builtin_amdgcn_global_load_lds(
      (const __attribute__((address_space(1))) void*)(uintptr_t)(g),
      (__attribute__((address_space(3))) void*)(uint32_t)(uintptr_t)(s),
      16, 0, 0);
}

// ---- fused prolog: eig partial means (blocks 0..63) + x transpose (64..319)
__global__ __launch_bounds__(256) void k_pre(const float* __restrict__ eig,
                                             const float* __restrict__ x,
                                             float* __restrict__ part,
                                             u16* __restrict__ xT) {
  const int bid = blockIdx.x, t = threadIdx.x;
  if (bid < 64) {
    const int b = bid >> 5, chunk = bid & 31;
    const int d = t & 127, half = t >> 7;
    const float* p = eig + ((long)b * 4096 + chunk * 128 + half) * 128 + d;
    float s = 0.0f;
    for (int i = 0; i < 64; i++) s += p[(long)i * 256];
    __shared__ float red[256];
    red[t] = s;
    __syncthreads();
    if (t < 128) part[((long)b * 32 + chunk) * 128 + d] = red[t] + red[t + 128];
    return;
  }
  // x fp32 [4096][128] -> xT bf16 [128][4096], 64x64 tiles (proven r3 code)
  const int q = bid - 64;           // 0..255
  const int b = q >> 7, rem = q & 127;
  const int tr = rem & 63, tc = rem >> 6;
  const float* I = x + (long)b * 524288;
  u16* O = xT + (long)b * 524288;
  __shared__ uint32_t L[64][33];
  const int r = t >> 2, cq = (t & 3) * 4;
  const float* src = I + (long)(tr * 64 + r) * 128 + tc * 64;
#pragma unroll
  for (int i = 0; i < 4; i++) {
    const float4 f = *(const float4*)(src + cq + 16 * i);
    const int c = cq + 16 * i;
    L[r][(c >> 1)]     = pkbf(f.x, f.y);
    L[r][(c >> 1) + 1] = pkbf(f.z, f.w);
  }
  __syncthreads();
  const int r0 = (t & 7) * 8;
#pragma unroll
  for (int p = 0; p < 2; p++) {
    const int c = (t >> 3) + 32 * p;
    uint32_t w[4];
#pragma unroll
    for (int i = 0; i < 4; i++) {
      const uint32_t w0 = L[r0 + 2 * i][c >> 1];
      const uint32_t w1 = L[r0 + 2 * i + 1][c >> 1];
      const u16 v0 = (c & 1) ? (u16)(w0 >> 16) : (u16)(w0 & 0xffff);
      const u16 v1 = (c & 1) ? (u16)(w1 >> 16) : (u16)(w1 & 0xffff);
      w[i] = (uint32_t)v0 | ((uint32_t)v1 << 16);
    }
    u32x4* dst = (u32x4*)(O + (long)(tc * 64 + c) * 4096 + tr * 64 + r0);
    *dst = u32x4{w[0], w[1], w[2], w[3]};
  }
}

// ---- fused weight folding (blocks 0..768) + pooled coefficients (769,770)
__global__ void k_foldcoeff(const float* __restrict__ WS, const float* __restrict__ WM,
                            const float* __restrict__ Ww, const float* __restrict__ bS,
                            const float* __restrict__ bM, const float* __restrict__ bw,
                            const float* __restrict__ part,
                            const float* __restrict__ Wa, const float* __restrict__ ba,
                            const float* __restrict__ Wb, const float* __restrict__ bb_,
                            const float* __restrict__ Ws, const float* __restrict__ bs,
                            u16* __restrict__ VT, float* __restrict__ cvec,
                            float* __restrict__ coeff) {
  const int q = blockIdx.x, e = threadIdx.x;
  if (q >= 769) {  // coefficient path, b = q - 769
    const int b = q - 769;
    __shared__ float sd[128];
    float s = 0.0f;
    for (int c = 0; c < 32; c++) s += part[((long)b * 32 + c) * 128 + e];
    sd[e] = s * (1.0f / 4096.0f);
    __syncthreads();
    if (e >= 15) return;
    const int kind = e / 5, r = e % 5;
    const float* W = (kind == 0) ? Wa : ((kind == 1) ? Wb : Ws);
    float v = 0.0f;
    for (int d = 0; d < 128; d++) v += sd[d] * W[d * 5 + r];
    v += (kind == 0) ? ba[r] : ((kind == 1) ? bb_[r] : bs[r]);
    if (kind == 2) v = 5.0f / (1.0f + __expf(-v));
    coeff[b * 16 + kind * 5 + r] = v;
    return;
  }
  if (q == 768) {
    float s = bw[e];
    for (int k = 0; k < 128; k++) {
      float t = bS[k];
#pragma unroll
      for (int j = 0; j < 5; j++) t += bM[j * 128 + k];
      s += t * Ww[k * 128 + e];
    }
    cvec[e] = s;
    return;
  }
  const int f = q >> 7, d = q & 127;
  const float* Frow = (f == 0) ? (WS + d * 128) : (WM + ((long)(f - 1) * 128 + d) * 128);
  float s = 0.0f;
  for (int k = 0; k < 128; k++) s += Frow[k] * Ww[k * 128 + e];
  VT[(long)e * 768 + f * 128 + d] = f2bf(s);
}

// ---- reduce 8 split-K slices of xt, apply Chebyshev filters, emit Mod bf16
__global__ void k_filter(const float* __restrict__ eig, const float* __restrict__ xs,
                         const float* __restrict__ coeff, u16* __restrict__ Mod) {
  const int b = blockIdx.y;
  const int n = blockIdx.x * 2 + (threadIdx.x >> 7);
  const int d = threadIdx.x & 127;
  const long ridx = (long)b * 4096 + n;
  const long off = ridx * 128 + d;
  const float e = eig[off];
  float xv = 0.0f;
#pragma unroll
  for (int s = 0; s < 8; s++) xv += xs[off + (long)s * 1048576];
  const float* cf = coeff + b * 16;
  float To = 1.0f, Tev = e;
  float h = cf[5];
#pragma unroll
  for (int i = 1; i < 5; i++) {
    To = 2.0f * e * Tev - To;
    Tev = 2.0f * e * To - Tev;
    h += cf[5 + i] * To;
  }
  u16* row = Mod + ridx * 768;
  row[d] = f2bf(h * xv);
#pragma unroll
  for (int j = 0; j < 5; j++) {
    const float sx = cf[10 + j] * e;
    float To2 = 1.0f, Te2 = sx;
    float g = cf[0] * Te2;
#pragma unroll
    for (int i = 1; i < 5; i++) {
      To2 = 2.0f * sx * Te2 - To2;
      Te2 = 2.0f * sx * To2 - Te2;
      g += cf[i] * Te2;
    }
    row[(j + 1) * 128 + d] = f2bf(g * xv);
  }
}

// ---- out = sum of 8 GEMM3 slices + cvec
__global__ void k_outred(const float* __restrict__ os, const float* __restrict__ cvec,
                         float* __restrict__ out) {
  const long i = (long)blockIdx.x * 256 + threadIdx.x;
  float4 r = *(const float4*)(os + 4 * i);
#pragma unroll
  for (int s = 1; s < 8; s++) {
    const float4 t = *(const float4*)(os + 4 * i + (long)s * 1048576);
    r.x += t.x; r.y += t.y; r.z += t.z; r.w += t.w;
  }
  const float4 cv = *(const float4*)(cvec + (i & 31) * 4);
  r.x += cv.x; r.y += cv.y; r.z += cv.z; r.w += cv.w;
  *(float4*)(out + 4 * i) = r;
}

// ---- GEMM: C[row][col] = sum_k A[row][k]*B[col][k]
// AT: 0 = bf16 [row][K] via global_load_lds; 1 = fp32 [row][K] reg-convert (conflict-free b128)
// BT: 0 = bf16 [col][K] via global_load_lds; 2 = fp32 [k][col] transposing stage, pad-17
// CT: 0 = fp32 slice store (row-major); 1 = bf16 row-major; 2 = fp32 slice store TRANSPOSED
template <int AT, int BT, int CT>
__global__ __launch_bounds__(256) void k_gemm(
    const void* __restrict__ A, long sA, int lda,
    const void* __restrict__ B, long sB, int ldb,
    void* __restrict__ C, long sC, int ldc, long kslice,
    int K, int kchunk, int m_tiles) {
  __shared__ __align__(16) u16 As[128 * 32];
  __shared__ __align__(16) u16 Bs[128 * 34 + 64];  // padded variant needs 128*17 words
  const int bb = blockIdx.z, ks = blockIdx.y;
  const int tm = blockIdx.x % m_tiles, tn = blockIdx.x / m_tiles;
  const int tid = threadIdx.x, wave = tid >> 6, lane = tid & 63;
  const int wm = (wave >> 1) * 64, wn = (wave & 1) * 64;
  f32x4 acc[4][4];
#pragma unroll
  for (int i = 0; i < 4; i++)
#pragma unroll
    for (int j = 0; j < 4; j++)
#pragma unroll
      for (int r = 0; r < 4; r++) acc[i][j][r] = 0.0f;
  const int a_off = (wm + (lane & 15)) * 64 + (lane >> 4) * 16;
  const int b_off = (BT == 2) ? ((wn + (lane & 15)) * 68 + (lane >> 4) * 16)
                              : ((wn + (lane & 15)) * 64 + (lane >> 4) * 16);
  const int b_nt_stride = (BT == 2) ? 1088 : 1024;
  const int srow = wave * 32 + (lane >> 2);
  const int scol = (lane & 3) * 8;
  for (int k0 = 0; k0 < kchunk; k0 += 32) {
    const int kb = ks * kchunk + k0;
    // ---- stage A (128 rows x 32 k, bf16 LDS rows of 64 B)
    if constexpr (AT == 0) {
      const u16* Ab = (const u16*)A + (long)bb * sA + (long)tm * 128 * lda + kb;
#pragma unroll
      for (int i = 0; i < 2; i++)
        gl_lds16(Ab + (long)(srow + i * 16) * lda + scol,
                 (char*)As + (wave * 32 + i * 16) * 64);
    } else {
      // fp32 rows, thread t: row = t>>2 (+64), k = (t&3)*8..+8, b128 write at tid*16
      const float* Af = (const float*)A + (long)bb * sA + (long)tm * 128 * lda + kb;
      const float* s0 = Af + (long)(tid >> 2) * lda + (tid & 3) * 8;
      const float4 f0 = *(const float4*)(s0);
      const float4 f1 = *(const float4*)(s0 + 4);
      *(u32x4*)((char*)As + tid * 16) =
          u32x4{pkbf(f0.x, f0.y), pkbf(f0.z, f0.w), pkbf(f1.x, f1.y), pkbf(f1.z, f1.w)};
      const float* s1 = s0 + (long)64 * lda;
      const float4 g0 = *(const float4*)(s1);
      const float4 g1 = *(const float4*)(s1 + 4);
      *(u32x4*)((char*)As + 4096 + tid * 16) =
          u32x4{pkbf(g0.x, g0.y), pkbf(g0.z, g0.w), pkbf(g1.x, g1.y), pkbf(g1.z, g1.w)};
    }
    // ---- stage B
    if constexpr (BT == 0) {
      const u16* Bb = (const u16*)B + (long)bb * sB + (long)tn * 128 * ldb + kb;
#pragma unroll
      for (int i = 0; i < 2; i++)
        gl_lds16(Bb + (long)(srow + i * 16) * ldb + scol,
                 (char*)Bs + (wave * 32 + i * 16) * 64);
    } else {
      // fp32 [k][col]: thread t: k-pair q = t&15, col-chunk cb = t>>4 (8 cols)
      // LDS layout: col stride 17 words (68 B), word (col*17 + q) = ks {2q, 2q+1}
      const int q = tid & 15, cb = tid >> 4;
      const float* r0 = (const float*)B + (long)bb * sB + (long)(kb + 2 * q) * ldb +
                        tn * 128 + cb * 8;
      const float* r1 = r0 + ldb;
      const float4 a0 = *(const float4*)(r0);
      const float4 a1 = *(const float4*)(r0 + 4);
      const float4 c0 = *(const float4*)(r1);
      const float4 c1 = *(const float4*)(r1 + 4);
      uint32_t* dw = (uint32_t*)Bs;
      const int base = (cb * 8) * 17 + q;
      dw[base + 0 * 17] = pkbf(a0.x, c0.x);
      dw[base + 1 * 17] = pkbf(a0.y, c0.y);
      dw[base + 2 * 17] = pkbf(a0.z, c0.z);
      dw[base + 3 * 17] = pkbf(a0.w, c0.w);
      dw[base + 4 * 17] = pkbf(a1.x, c1.x);
      dw[base + 5 * 17] = pkbf(a1.y, c1.y);
      dw[base + 6 * 17] = pkbf(a1.z, c1.z);
      dw[base + 7 * 17] = pkbf(a1.w, c1.w);
    }
    __syncthreads();
    bf16x8 af[4], bfr[4];
#pragma unroll
    for (int mt = 0; mt < 4; mt++)
      af[mt] = *(const bf16x8*)((const char*)As + a_off + mt * 1024);
#pragma unroll
    for (int nt = 0; nt < 4; nt++)
      bfr[nt] = *(const bf16x8*)((const char*)Bs + b_off + nt * b_nt_stride);
#pragma unroll
    for (int mt = 0; mt < 4; mt++)
#pragma unroll
      for (int nt = 0; nt < 4; nt++)
        acc[mt][nt] = __builtin_amdgcn_mfma_f32_16x16x32_bf16(af[mt], bfr[nt], acc[mt][nt], 0, 0, 0);
    __syncthreads();
  }
  const int lr = (lane >> 4) * 4, lc = lane & 15;
  if constexpr (CT == 1) {
    u16* Cb = (u16*)C + (long)bb * sC;
#pragma unroll
    for (int mt = 0; mt < 4; mt++)
#pragma unroll
      for (int nt = 0; nt < 4; nt++) {
        const int col = tn * 128 + wn + nt * 16 + lc;
#pragma unroll
        for (int r = 0; r < 4; r++) {
          const int row = tm * 128 + wm + mt * 16 + lr + r;
          Cb[(long)row * ldc + col] = f2bf(acc[mt][nt][r]);
        }
      }
  } else if constexpr (CT == 0) {
    float* Cf = (float*)C + (long)bb * sC + (long)ks * kslice;
#pragma unroll
    for (int mt = 0; mt < 4; mt++)
#pragma unroll
      for (int nt = 0; nt < 4; nt++) {
        const int col = tn * 128 + wn + nt * 16 + lc;
#pragma unroll
        for (int r = 0; r < 4; r++) {
          const int row = tm * 128 + wm + mt * 16 + lr + r;
          Cf[(long)row * ldc + col] = acc[mt][nt][r];
        }
      }
  } else {  // CT == 2: transposed store, addr = col*ldc + row
    float* Cf = (float*)C + (long)bb * sC + (long)ks * kslice;
#pragma unroll
    for (int mt = 0; mt < 4; mt++)
#pragma unroll
      for (int nt = 0; nt < 4; nt++) {
        const int col = tn * 128 + wn + nt * 16 + lc;
#pragma unroll
        for (int r = 0; r < 4; r++) {
          const int row = tm * 128 + wm + mt * 16 + lr + r;
          Cf[(long)col * ldc + row] = acc[mt][nt][r];
        }
      }
  }
}

extern "C" void kernel_launch(void* const* d_in, const int* in_sizes, int n_in,
                              void* d_out, int out_size, void* d_ws, size_t ws_size,
                              hipStream_t stream) {
  const float* eig = (const float*)d_in[0];
  const float* x   = (const float*)d_in[1];
  const float* U   = (const float*)d_in[2];
  const float* Wa  = (const float*)d_in[3];
  const float* ba  = (const float*)d_in[4];
  const float* Wb  = (const float*)d_in[5];
  const float* bb  = (const float*)d_in[6];
  const float* Ws  = (const float*)d_in[7];
  const float* bs  = (const float*)d_in[8];
  const float* WSm = (const float*)d_in[9];
  const float* bS  = (const float*)d_in[10];
  const float* WM  = (const float*)d_in[11];
  const float* bM  = (const float*)d_in[12];
  const float* Ww  = (const float*)d_in[13];
  const float* bw  = (const float*)d_in[14];

  char* ws = (char*)d_ws;
  float* xs   = (float*)(ws + 0);          // 33,554,432 B (8 split-K slices) — aliased with os
  float* os   = (float*)(ws + 0);          // GEMM3 slices reuse xs region (xs dead after filter)
  u16*   Mod  = (u16*)(ws + 33554432);     // 12,582,912 B
  u16*   xT   = (u16*)(ws + 46137344);     //  2,097,152 B
  u16*   wT   = (u16*)(ws + 48234496);     //  2,097,152 B
  u16*   VT   = (u16*)(ws + 50331648);     //    196,608 B
  float* part = (float*)(ws + 50528256);   //     32,768 B
  float* coef = (float*)(ws + 50561024);   //        128 B
  float* cvec = (float*)(ws + 50561152);   //        512 B
  float* outp = (float*)d_out;

  if (ws_size < (size_t)50561664) return;  // workspace guard

  // prolog: eig partial means + x transpose (bf16 [d][m])
  k_pre<<<320, 256, 0, stream>>>(eig, x, part, xT);
  // weight folding + bias vector + pooled coefficients
  k_foldcoeff<<<771, 128, 0, stream>>>(WSm, WM, Ww, bS, bM, bw, part,
                                       Wa, ba, Wb, bb, Ws, bs, VT, cvec, coef);

  // GEMM1: xt[n][d] = sum_m U[m][n] x[m][d]
  //   A = xT bf16 [d][m] (gl_lds), B = U fp32 [m][n] transposing stage,
  //   C transposed-store -> xs slices [n][d]; split-K=8
  k_gemm<0, 2, 2><<<dim3(32, 8, 2), 256, 0, stream>>>(
      xT, 524288L, 4096, U, 16777216L, 4096,
      (void*)xs, 524288L, 128, 1048576L, 4096, 512, 1);

  // reduce slices + Chebyshev filters -> Mod bf16
  k_filter<<<dim3(2048, 2), 256, 0, stream>>>(eig, xs, coef, Mod);

  // GEMM2: wT[e][m] = sum_k VT[e][k] Mod[m][k]; K=768, no split-K, bf16 out
  k_gemm<0, 0, 1><<<dim3(32, 1, 2), 256, 0, stream>>>(
      VT, 0L, 768, Mod, 3145728L, 768,
      (void*)wT, 524288L, 4096, 0L, 768, 768, 1);

  // GEMM3: out[n][e] = sum_m U[n][m] wT[e][m]; A = U fp32 rows, B = wT gl_lds; split-K=8
  k_gemm<1, 0, 0><<<dim3(32, 8, 2), 256, 0, stream>>>(
      U, 16777216L, 4096, wT, 524288L, 4096,
      (void*)os, 524288L, 128, 1048576L, 4096, 512, 32);

  // final reduce + bias
  k_outred<<<1024, 256, 0, stream>>>(os, cvec, outp);
}

// Round 7
// 293.902 us; speedup vs baseline: 1.3341x; 1.0644x over previous
//
#include <hip/hip_runtime.h>
#include <hip/hip_bf16.h>
#include <stdint.h>

typedef unsigned short u16;
typedef __attribute__((ext_vector_type(8))) short bf16x8;
typedef __attribute__((ext_vector_type(4))) float f32x4;
typedef __attribute__((ext_vector_type(4))) uint32_t u32x4;

__device__ inline u16 f2bf(float f) {
  union { float f; uint32_t u; } v; v.f = f;
  uint32_t u = v.u;
  u += 0x7FFFu + ((u >> 16) & 1u);
  return (u16)(u >> 16);
}
__device__ inline uint32_t pkbf(float a, float b) {
  union { __hip_bfloat162 h; uint32_t u; } c;
  c.h = __float22bfloat162_rn(float2{a, b});
  return c.u;
}
__device__ inline float bf2f(u16 h) {
  union { uint32_t u; float f; } v; v.u = (uint32_t)h << 16; return v.f;
}
__device__ inline void gl_lds16(const void* g, void* s) {
  __builtin_amdgcn_global_load_lds(
      (const __attribute__((address_space(1))) void*)(uintptr_t)(g),
      (__attribute__((address_space(3))) void*)(uint32_t)(uintptr_t)(s),
      16, 0, 0);
}

// ---- prolog: eig partial means (0..63) + x transpose (64..319)
//      + VT weight fold (320..703) + cvec (704)
__global__ __launch_bounds__(256) void k_pre(
    const float* __restrict__ eig, const float* __restrict__ x,
    const float* __restrict__ WS, const float* __restrict__ WM,
    const float* __restrict__ Ww, const float* __restrict__ bS,
    const float* __restrict__ bM, const float* __restrict__ bw,
    float* __restrict__ part, u16* __restrict__ xT,
    u16* __restrict__ VT, float* __restrict__ cvec) {
  const int bid = blockIdx.x, t = threadIdx.x;
  __shared__ float red[256];
  __shared__ uint32_t L[64][33];
  if (bid < 64) {
    const int b = bid >> 5, chunk = bid & 31;
    const int d = t & 127, half = t >> 7;
    const float* p = eig + ((long)b * 4096 + chunk * 128 + half) * 128 + d;
    float s = 0.0f;
    for (int i = 0; i < 64; i++) s += p[(long)i * 256];
    red[t] = s;
    __syncthreads();
    if (t < 128) part[((long)b * 32 + chunk) * 128 + d] = red[t] + red[t + 128];
    return;
  }
  if (bid < 320) {
    // x fp32 [4096][128] -> xT bf16 [128][4096], 64x64 tiles
    const int q = bid - 64;
    const int b = q >> 7, rem = q & 127;
    const int tr = rem & 63, tc = rem >> 6;
    const float* I = x + (long)b * 524288;
    u16* O = xT + (long)b * 524288;
    const int r = t >> 2, cq = (t & 3) * 4;
    const float* src = I + (long)(tr * 64 + r) * 128 + tc * 64;
#pragma unroll
    for (int i = 0; i < 4; i++) {
      const float4 f = *(const float4*)(src + cq + 16 * i);
      const int c = cq + 16 * i;
      L[r][(c >> 1)]     = pkbf(f.x, f.y);
      L[r][(c >> 1) + 1] = pkbf(f.z, f.w);
    }
    __syncthreads();
    const int r0 = (t & 7) * 8;
#pragma unroll
    for (int p = 0; p < 2; p++) {
      const int c = (t >> 3) + 32 * p;
      uint32_t w[4];
#pragma unroll
      for (int i = 0; i < 4; i++) {
        const uint32_t w0 = L[r0 + 2 * i][c >> 1];
        const uint32_t w1 = L[r0 + 2 * i + 1][c >> 1];
        const u16 v0 = (c & 1) ? (u16)(w0 >> 16) : (u16)(w0 & 0xffff);
        const u16 v1 = (c & 1) ? (u16)(w1 >> 16) : (u16)(w1 & 0xffff);
        w[i] = (uint32_t)v0 | ((uint32_t)v1 << 16);
      }
      u32x4* dst = (u32x4*)(O + (long)(tc * 64 + c) * 4096 + tr * 64 + r0);
      *dst = u32x4{w[0], w[1], w[2], w[3]};
    }
    return;
  }
  if (bid < 704) {
    // VT[e][f*128+d] = (F_f @ Ww)[d][e]; 2 q per block
    const int q = (bid - 320) * 2 + (t >> 7);
    const int e = t & 127;
    const int f = q >> 7, d = q & 127;
    const float* Frow = (f == 0) ? (WS + d * 128) : (WM + ((long)(f - 1) * 128 + d) * 128);
    float s = 0.0f;
    for (int k = 0; k < 128; k++) s += Frow[k] * Ww[k * 128 + e];
    VT[(long)e * 768 + f * 128 + d] = f2bf(s);
    return;
  }
  // cvec
  if (t >= 128) return;
  float s = bw[t];
  for (int k = 0; k < 128; k++) {
    float tv = bS[k];
#pragma unroll
    for (int j = 0; j < 5; j++) tv += bM[j * 128 + k];
    s += tv * Ww[k * 128 + t];
  }
  cvec[t] = s;
}

// ---- GEMM1: xs[ks][b][n][d] = partial sum_m U[m][n] * x[m][d]
// A = xT bf16 [d][m] via gl_lds; B = U fp32 [m][n] transposing stage (pad-17),
// register-prefetched. tn==32 blocks (ks==0) compute pooled coefficients.
__global__ __launch_bounds__(256) void k_gemm1(
    const u16* __restrict__ xT, const float* __restrict__ U,
    const float* __restrict__ part,
    const float* __restrict__ Wa, const float* __restrict__ ba,
    const float* __restrict__ Wb, const float* __restrict__ bb_,
    const float* __restrict__ Ws, const float* __restrict__ bs,
    float* __restrict__ xs, float* __restrict__ coeff) {
  const int tn = blockIdx.x, ks = blockIdx.y, bb = blockIdx.z;
  const int tid = threadIdx.x;
  __shared__ float sd[128];
  __shared__ __align__(16) u16 As[128 * 32];
  __shared__ __align__(16) u16 Bs[128 * 34 + 64];
  if (tn == 32) {
    if (ks != 0) return;
    if (tid < 128) {
      float s = 0.0f;
      for (int c = 0; c < 32; c++) s += part[((long)bb * 32 + c) * 128 + tid];
      sd[tid] = s * (1.0f / 4096.0f);
    }
    __syncthreads();
    if (tid >= 15) return;
    const int kind = tid / 5, r = tid % 5;
    const float* W = (kind == 0) ? Wa : ((kind == 1) ? Wb : Ws);
    float v = 0.0f;
    for (int d = 0; d < 128; d++) v += sd[d] * W[d * 5 + r];
    v += (kind == 0) ? ba[r] : ((kind == 1) ? bb_[r] : bs[r]);
    if (kind == 2) v = 5.0f / (1.0f + __expf(-v));
    coeff[bb * 16 + kind * 5 + r] = v;
    return;
  }
  const int wave = tid >> 6, lane = tid & 63;
  const int wm = (wave >> 1) * 64, wn = (wave & 1) * 64;
  f32x4 acc[4][4];
#pragma unroll
  for (int i = 0; i < 4; i++)
#pragma unroll
    for (int j = 0; j < 4; j++)
#pragma unroll
      for (int r = 0; r < 4; r++) acc[i][j][r] = 0.0f;
  const int a_off = (wm + (lane & 15)) * 64 + (lane >> 4) * 16;
  const int b_off = (wn + (lane & 15)) * 68 + (lane >> 4) * 16;
  const int srow = wave * 32 + (lane >> 2);
  const int scol = (lane & 3) * 8;
  const u16* Ab = xT + (long)bb * 524288 + ks * 512;
  const int q = tid & 15, cb = tid >> 4;
  const float* Bbase = U + (long)bb * 16777216 + tn * 128 + cb * 8;
  float4 ca0, ca1, cc0, cc1;
  {
    const float* r0 = Bbase + (long)(ks * 512 + 2 * q) * 4096;
    ca0 = *(const float4*)(r0); ca1 = *(const float4*)(r0 + 4);
    const float* r1 = r0 + 4096;
    cc0 = *(const float4*)(r1); cc1 = *(const float4*)(r1 + 4);
  }
  for (int k0 = 0; k0 < 512; k0 += 32) {
    // A async
#pragma unroll
    for (int i = 0; i < 2; i++)
      gl_lds16(Ab + (long)(srow + i * 16) * 4096 + k0 + scol,
               (char*)As + (wave * 32 + i * 16) * 64);
    // B LDS from prefetched regs
    {
      uint32_t* dw = (uint32_t*)Bs;
      const int base = (cb * 8) * 17 + q;
      dw[base + 0 * 17] = pkbf(ca0.x, cc0.x);
      dw[base + 1 * 17] = pkbf(ca0.y, cc0.y);
      dw[base + 2 * 17] = pkbf(ca0.z, cc0.z);
      dw[base + 3 * 17] = pkbf(ca0.w, cc0.w);
      dw[base + 4 * 17] = pkbf(ca1.x, cc1.x);
      dw[base + 5 * 17] = pkbf(ca1.y, cc1.y);
      dw[base + 6 * 17] = pkbf(ca1.z, cc1.z);
      dw[base + 7 * 17] = pkbf(ca1.w, cc1.w);
    }
    __syncthreads();
    // prefetch next B tile (clamped on last iter — loaded but unused, no UB)
    const int kn = (k0 + 32 < 512) ? (k0 + 32) : k0;
    float4 na0, na1, nc0, nc1;
    {
      const float* r0 = Bbase + (long)(ks * 512 + kn + 2 * q) * 4096;
      na0 = *(const float4*)(r0); na1 = *(const float4*)(r0 + 4);
      const float* r1 = r0 + 4096;
      nc0 = *(const float4*)(r1); nc1 = *(const float4*)(r1 + 4);
    }
    bf16x8 af[4], bfr[4];
#pragma unroll
    for (int mt = 0; mt < 4; mt++)
      af[mt] = *(const bf16x8*)((const char*)As + a_off + mt * 1024);
#pragma unroll
    for (int nt = 0; nt < 4; nt++)
      bfr[nt] = *(const bf16x8*)((const char*)Bs + b_off + nt * 1088);
#pragma unroll
    for (int mt = 0; mt < 4; mt++)
#pragma unroll
      for (int nt = 0; nt < 4; nt++)
        acc[mt][nt] = __builtin_amdgcn_mfma_f32_16x16x32_bf16(af[mt], bfr[nt], acc[mt][nt], 0, 0, 0);
    __syncthreads();
    ca0 = na0; ca1 = na1; cc0 = nc0; cc1 = nc1;
  }
  // transposed fp32 slice store: xs[ks][b][n][d]
  const int lr = (lane >> 4) * 4, lc = lane & 15;
  float* Cf = xs + (long)bb * 524288 + (long)ks * 1048576;
#pragma unroll
  for (int mt = 0; mt < 4; mt++)
#pragma unroll
    for (int nt = 0; nt < 4; nt++) {
      const int col = tn * 128 + wn + nt * 16 + lc;
#pragma unroll
      for (int r = 0; r < 4; r++) {
        const int row = wm + mt * 16 + lr + r;
        Cf[(long)col * 128 + row] = acc[mt][nt][r];
      }
    }
}

// ---- reduce 8 split-K slices, Chebyshev filters -> Mod bf16
__global__ void k_filter(const float* __restrict__ eig, const float* __restrict__ xs,
                         const float* __restrict__ coeff, u16* __restrict__ Mod) {
  const int b = blockIdx.y;
  const int n = blockIdx.x * 2 + (threadIdx.x >> 7);
  const int d = threadIdx.x & 127;
  const long ridx = (long)b * 4096 + n;
  const long off = ridx * 128 + d;
  const float e = eig[off];
  float xv = 0.0f;
#pragma unroll
  for (int s = 0; s < 8; s++) xv += xs[off + (long)s * 1048576];
  const float* cf = coeff + b * 16;
  float To = 1.0f, Tev = e;
  float h = cf[5];
#pragma unroll
  for (int i = 1; i < 5; i++) {
    To = 2.0f * e * Tev - To;
    Tev = 2.0f * e * To - Tev;
    h += cf[5 + i] * To;
  }
  u16* row = Mod + ridx * 768;
  row[d] = f2bf(h * xv);
#pragma unroll
  for (int j = 0; j < 5; j++) {
    const float sx = cf[10 + j] * e;
    float To2 = 1.0f, Te2 = sx;
    float g = cf[0] * Te2;
#pragma unroll
    for (int i = 1; i < 5; i++) {
      To2 = 2.0f * sx * Te2 - To2;
      Te2 = 2.0f * sx * To2 - Te2;
      g += cf[i] * Te2;
    }
    row[(j + 1) * 128 + d] = f2bf(g * xv);
  }
}

// ---- GEMM2: wT[e][m] = sum_k VT[e][k] Mod[m][k]; K=768, bf16 out
__global__ __launch_bounds__(256) void k_gemm2(
    const u16* __restrict__ VT, const u16* __restrict__ Mod, u16* __restrict__ wT) {
  const int tn = blockIdx.x, bb = blockIdx.z;
  __shared__ __align__(16) u16 As[128 * 32];
  __shared__ __align__(16) u16 Bs[128 * 32];
  const int tid = threadIdx.x, wave = tid >> 6, lane = tid & 63;
  const int wm = (wave >> 1) * 64, wn = (wave & 1) * 64;
  f32x4 acc[4][4];
#pragma unroll
  for (int i = 0; i < 4; i++)
#pragma unroll
    for (int j = 0; j < 4; j++)
#pragma unroll
      for (int r = 0; r < 4; r++) acc[i][j][r] = 0.0f;
  const int a_off = (wm + (lane & 15)) * 64 + (lane >> 4) * 16;
  const int b_off = (wn + (lane & 15)) * 64 + (lane >> 4) * 16;
  const int srow = wave * 32 + (lane >> 2);
  const int scol = (lane & 3) * 8;
  const u16* Bb = Mod + (long)bb * 3145728 + (long)tn * 128 * 768;
  for (int k0 = 0; k0 < 768; k0 += 32) {
#pragma unroll
    for (int i = 0; i < 2; i++) {
      gl_lds16(VT + (long)(srow + i * 16) * 768 + k0 + scol,
               (char*)As + (wave * 32 + i * 16) * 64);
      gl_lds16(Bb + (long)(srow + i * 16) * 768 + k0 + scol,
               (char*)Bs + (wave * 32 + i * 16) * 64);
    }
    __syncthreads();
    bf16x8 af[4], bfr[4];
#pragma unroll
    for (int mt = 0; mt < 4; mt++)
      af[mt] = *(const bf16x8*)((const char*)As + a_off + mt * 1024);
#pragma unroll
    for (int nt = 0; nt < 4; nt++)
      bfr[nt] = *(const bf16x8*)((const char*)Bs + b_off + nt * 1024);
#pragma unroll
    for (int mt = 0; mt < 4; mt++)
#pragma unroll
      for (int nt = 0; nt < 4; nt++)
        acc[mt][nt] = __builtin_amdgcn_mfma_f32_16x16x32_bf16(af[mt], bfr[nt], acc[mt][nt], 0, 0, 0);
    __syncthreads();
  }
  const int lr = (lane >> 4) * 4, lc = lane & 15;
  u16* Cb = wT + (long)bb * 524288;
#pragma unroll
  for (int mt = 0; mt < 4; mt++)
#pragma unroll
    for (int nt = 0; nt < 4; nt++) {
      const int col = tn * 128 + wn + nt * 16 + lc;
#pragma unroll
      for (int r = 0; r < 4; r++) {
        const int row = wm + mt * 16 + lr + r;
        Cb[(long)row * 4096 + col] = f2bf(acc[mt][nt][r]);
      }
    }
}

// ---- GEMM3: os16[ks][b][n][e] = bf16 partial sum_m U[n][m] wT[e][m]
// A = U fp32 rows, register-prefetched; B = wT bf16 via gl_lds.
__global__ __launch_bounds__(256) void k_gemm3(
    const float* __restrict__ U, const u16* __restrict__ wT, u16* __restrict__ os16) {
  const int tm = blockIdx.x, ks = blockIdx.y, bb = blockIdx.z;
  __shared__ __align__(16) u16 As[128 * 32];
  __shared__ __align__(16) u16 Bs[128 * 32];
  const int tid = threadIdx.x, wave = tid >> 6, lane = tid & 63;
  const int wm = (wave >> 1) * 64, wn = (wave & 1) * 64;
  f32x4 acc[4][4];
#pragma unroll
  for (int i = 0; i < 4; i++)
#pragma unroll
    for (int j = 0; j < 4; j++)
#pragma unroll
      for (int r = 0; r < 4; r++) acc[i][j][r] = 0.0f;
  const int a_off = (wm + (lane & 15)) * 64 + (lane >> 4) * 16;
  const int b_off = (wn + (lane & 15)) * 64 + (lane >> 4) * 16;
  const int srow = wave * 32 + (lane >> 2);
  const int scol = (lane & 3) * 8;
  const float* Abase = U + (long)bb * 16777216 +
                       (long)(tm * 128 + (tid >> 2)) * 4096 + (tid & 3) * 8;
  const u16* Bb = wT + (long)bb * 524288 + ks * 512;
  float4 cf0, cf1, cg0, cg1;
  {
    const float* s0 = Abase + ks * 512;
    cf0 = *(const float4*)(s0); cf1 = *(const float4*)(s0 + 4);
    const float* s1 = s0 + 262144;
    cg0 = *(const float4*)(s1); cg1 = *(const float4*)(s1 + 4);
  }
  for (int k0 = 0; k0 < 512; k0 += 32) {
    // B async
#pragma unroll
    for (int i = 0; i < 2; i++)
      gl_lds16(Bb + (long)(srow + i * 16) * 4096 + k0 + scol,
               (char*)Bs + (wave * 32 + i * 16) * 64);
    // A LDS from prefetched regs (conflict-free b128)
    *(u32x4*)((char*)As + tid * 16) =
        u32x4{pkbf(cf0.x, cf0.y), pkbf(cf0.z, cf0.w), pkbf(cf1.x, cf1.y), pkbf(cf1.z, cf1.w)};
    *(u32x4*)((char*)As + 4096 + tid * 16) =
        u32x4{pkbf(cg0.x, cg0.y), pkbf(cg0.z, cg0.w), pkbf(cg1.x, cg1.y), pkbf(cg1.z, cg1.w)};
    __syncthreads();
    const int kn = (k0 + 32 < 512) ? (k0 + 32) : k0;
    float4 nf0, nf1, ng0, ng1;
    {
      const float* s0 = Abase + ks * 512 + kn;
      nf0 = *(const float4*)(s0); nf1 = *(const float4*)(s0 + 4);
      const float* s1 = s0 + 262144;
      ng0 = *(const float4*)(s1); ng1 = *(const float4*)(s1 + 4);
    }
    bf16x8 af[4], bfr[4];
#pragma unroll
    for (int mt = 0; mt < 4; mt++)
      af[mt] = *(const bf16x8*)((const char*)As + a_off + mt * 1024);
#pragma unroll
    for (int nt = 0; nt < 4; nt++)
      bfr[nt] = *(const bf16x8*)((const char*)Bs + b_off + nt * 1024);
#pragma unroll
    for (int mt = 0; mt < 4; mt++)
#pragma unroll
      for (int nt = 0; nt < 4; nt++)
        acc[mt][nt] = __builtin_amdgcn_mfma_f32_16x16x32_bf16(af[mt], bfr[nt], acc[mt][nt], 0, 0, 0);
    __syncthreads();
    cf0 = nf0; cf1 = nf1; cg0 = ng0; cg1 = ng1;
  }
  const int lr = (lane >> 4) * 4, lc = lane & 15;
  // slice layout: [ks][bb][n][e] — ks stride 1,048,576 elems, bb stride 524,288 elems
  u16* Cb = os16 + (long)ks * 1048576 + (long)bb * 524288;
#pragma unroll
  for (int mt = 0; mt < 4; mt++)
#pragma unroll
    for (int nt = 0; nt < 4; nt++) {
      const int col = wn + nt * 16 + lc;
#pragma unroll
      for (int r = 0; r < 4; r++) {
        const int row = tm * 128 + wm + mt * 16 + lr + r;
        Cb[(long)row * 128 + col] = f2bf(acc[mt][nt][r]);
      }
    }
}

// ---- out = sum of 8 bf16 slices + cvec
__global__ void k_outred(const u16* __restrict__ os16, const float* __restrict__ cvec,
                         float* __restrict__ out) {
  const long i = (long)blockIdx.x * 256 + threadIdx.x;
  const long j4 = i * 4;
  float4 r = {0.0f, 0.0f, 0.0f, 0.0f};
#pragma unroll
  for (int s = 0; s < 8; s++) {
    const uint2 v = *(const uint2*)(os16 + j4 + (long)s * 1048576);
    r.x += bf2f((u16)(v.x & 0xffff));
    r.y += bf2f((u16)(v.x >> 16));
    r.z += bf2f((u16)(v.y & 0xffff));
    r.w += bf2f((u16)(v.y >> 16));
  }
  const float4 cv = *(const float4*)(cvec + (i & 31) * 4);
  r.x += cv.x; r.y += cv.y; r.z += cv.z; r.w += cv.w;
  *(float4*)(out + j4) = r;
}

extern "C" void kernel_launch(void* const* d_in, const int* in_sizes, int n_in,
                              void* d_out, int out_size, void* d_ws, size_t ws_size,
                              hipStream_t stream) {
  const float* eig = (const float*)d_in[0];
  const float* x   = (const float*)d_in[1];
  const float* U   = (const float*)d_in[2];
  const float* Wa  = (const float*)d_in[3];
  const float* ba  = (const float*)d_in[4];
  const float* Wb  = (const float*)d_in[5];
  const float* bb  = (const float*)d_in[6];
  const float* Ws  = (const float*)d_in[7];
  const float* bs  = (const float*)d_in[8];
  const float* WSm = (const float*)d_in[9];
  const float* bS  = (const float*)d_in[10];
  const float* WM  = (const float*)d_in[11];
  const float* bM  = (const float*)d_in[12];
  const float* Ww  = (const float*)d_in[13];
  const float* bw  = (const float*)d_in[14];

  char* ws = (char*)d_ws;
  float* xs   = (float*)(ws + 0);          // 33,554,432 B (8 fp32 split-K slices)
  u16*   os16 = (u16*)(ws + 0);            // 16,777,216 B — aliases xs (xs dead after filter)
  u16*   Mod  = (u16*)(ws + 33554432);     // 12,582,912 B
  u16*   xT   = (u16*)(ws + 46137344);     //  2,097,152 B
  u16*   wT   = (u16*)(ws + 48234496);     //  2,097,152 B
  u16*   VT   = (u16*)(ws + 50331648);     //    196,608 B
  float* part = (float*)(ws + 50528256);   //     32,768 B
  float* coef = (float*)(ws + 50561024);   //        128 B
  float* cvec = (float*)(ws + 50561152);   //        512 B
  float* outp = (float*)d_out;

  if (ws_size < (size_t)50561664) return;  // workspace guard

  // prolog: eig means + x transpose + VT fold + cvec (one launch)
  k_pre<<<705, 256, 0, stream>>>(eig, x, WSm, WM, Ww, bS, bM, bw, part, xT, VT, cvec);

  // GEMM1 (+ pooled coefficients in tn==32 blocks)
  k_gemm1<<<dim3(33, 8, 2), 256, 0, stream>>>(xT, U, part, Wa, ba, Wb, bb, Ws, bs, xs, coef);

  // slice reduce + Chebyshev filters -> Mod bf16
  k_filter<<<dim3(2048, 2), 256, 0, stream>>>(eig, xs, coef, Mod);

  // GEMM2
  k_gemm2<<<dim3(32, 1, 2), 256, 0, stream>>>(VT, Mod, wT);

  // GEMM3 -> bf16 slices
  k_gemm3<<<dim3(32, 8, 2), 256, 0, stream>>>(U, wT, os16);

  // final reduce + bias
  k_outred<<<1024, 256, 0, stream>>>(os16, cvec, outp);
}